// Round 10
// baseline (1640.894 us; speedup 1.0000x reference)
//
#include <hip/hip_runtime.h>

// SparseCoding fused persistent kernel, fp32 VALU (R10 = R9 + load packing +
// occupancy). Arithmetic chains bit-identical to R1/R9 (absmax must stay
// 4.882812e-4).
// Changes vs R9 (scheduling/layout only):
//  - W4  pack: W4[(j>>2)][i][j&3]  -> phase-1 reads ONE coalesced dwordx4 per
//    4-j (was 4 scalar loads + 64-bit addr math each).
//  - Wt4 pack: Wt4[(i>>2)][j][i&3] -> phase-2 reads TWO coalesced dwordx4 per
//    4-i, 32B/lane contiguous (was 4x 8B f32x2).
//  - inp tile moved LDS -> registers (only read at per-thread indices):
//    LDS 48KB -> 40KB -> 4 blocks/CU, __launch_bounds__(256,4), 16 waves/CU.
// Diagnostic round: big drop => R9's 2.5x VALU-issue overhead was loads/addr;
// stuck at ~1.5ms => LDS broadcast pipe is the limit (next: SGPR broadcast).

#define BSZ   32768
#define DIN   128
#define DOUT  512
#define RTILE 16
#define NSTEP 10
#define NBLOCKS (BSZ / RTILE)   // 2048

// pack both layouts in one kernel (one-time, 256 KB each into ws)
__global__ void sc_pack(const float* __restrict__ W, float* __restrict__ W4,
                        float* __restrict__ Wt4) {
    const int tid = blockIdx.x * blockDim.x + threadIdx.x;  // 0..65535
    const int j = tid >> 7;      // 0..511 (coalesced read of W row-major)
    const int i = tid & 127;     // 0..127
    const float v = W[j * DIN + i];
    W4 [(j >> 2) * 512  + i * 4 + (j & 3)] = v;   // [j/4][i][j%4]
    Wt4[(i >> 2) * 2048 + j * 4 + (i & 3)] = v;   // [i/4][j][i%4]
}

__global__ __launch_bounds__(256, 4)
void sc_fused(const float* __restrict__ inp, const float4* __restrict__ W4,
              const float4* __restrict__ Wt4, float* __restrict__ out)
{
    __shared__ float x_lds[RTILE][DOUT];    // 32 KB
    __shared__ float d_lds[RTILE][DIN];     //  8 KB   (total 40 KB -> 4 blk/CU)

    const int t = threadIdx.x;
    const int row0 = blockIdx.x * RTILE;

    const int i_p1 = t & 127;        // phase-1 column (0..127)
    const int rg   = (t >> 7) * 8;   // phase-1 row group (0 or 8)
    const int j0   = 2 * t;          // phase-2/update column pair (0..510)

    // Per-thread RMSProp state
    float a1[RTILE][2];
    float a2[RTILE][2];
#pragma unroll
    for (int r = 0; r < RTILE; ++r) {
        a1[r][0] = a1[r][1] = 0.f;
        a2[r][0] = a2[r][1] = 0.f;
    }

    // inp values this thread needs in phase 1 (registers, not LDS)
    float inr[8];
#pragma unroll
    for (int rr = 0; rr < 8; ++rr)
        inr[rr] = inp[(row0 + rg + rr) * DIN + i_p1];

    // init x = 0
    for (int k = t; k < RTILE * DOUT; k += 256) (&x_lds[0][0])[k] = 0.f;
    __syncthreads();

    // thread-fixed base pointers
    const float4* __restrict__ w4p  = W4 + i_p1;          // + (j>>2)*128
    const float4* __restrict__ wt4p = Wt4 + j0;           // + (i>>2)*512 (+1)

    for (int step = 0; step < NSTEP; ++step) {
        // ---- phase 1: d = x @ W - inp  (serial j-chain, identical to R1) ----
        {
            float acc[8];
#pragma unroll
            for (int rr = 0; rr < 8; ++rr) acc[rr] = 0.f;

#pragma unroll 2
            for (int jb = 0; jb < DOUT / 4; ++jb) {
                const float4 wv = w4p[jb * 128];   // W[4j..4j+3][i_p1], 16B/lane coalesced
#pragma unroll
                for (int rr = 0; rr < 8; ++rr) {
                    const float4 xv = *(const float4*)&x_lds[rg + rr][jb * 4];  // LDS broadcast
                    acc[rr] = fmaf(xv.x, wv.x, acc[rr]);
                    acc[rr] = fmaf(xv.y, wv.y, acc[rr]);
                    acc[rr] = fmaf(xv.z, wv.z, acc[rr]);
                    acc[rr] = fmaf(xv.w, wv.w, acc[rr]);
                }
            }
#pragma unroll
            for (int rr = 0; rr < 8; ++rr)
                d_lds[rg + rr][i_p1] = acc[rr] - inr[rr];
        }
        __syncthreads();

        // ---- phase 2: gacc = d @ W^T (serial i-chain, identical to R1) ----
        {
            float acc[RTILE][2];
#pragma unroll
            for (int r = 0; r < RTILE; ++r) acc[r][0] = acc[r][1] = 0.f;

#pragma unroll 2
            for (int ib = 0; ib < DIN / 4; ++ib) {
                // wqa = W[j0][4i..4i+3], wqb = W[j0+1][4i..4i+3]; 32B/lane contiguous
                const float4 wqa = wt4p[ib * 512];
                const float4 wqb = wt4p[ib * 512 + 1];
#pragma unroll
                for (int r = 0; r < RTILE; ++r) {
                    const float4 dv = *(const float4*)&d_lds[r][ib * 4];  // LDS broadcast
                    acc[r][0] = fmaf(dv.x, wqa.x, acc[r][0]);
                    acc[r][0] = fmaf(dv.y, wqa.y, acc[r][0]);
                    acc[r][0] = fmaf(dv.z, wqa.z, acc[r][0]);
                    acc[r][0] = fmaf(dv.w, wqa.w, acc[r][0]);
                    acc[r][1] = fmaf(dv.x, wqb.x, acc[r][1]);
                    acc[r][1] = fmaf(dv.y, wqb.y, acc[r][1]);
                    acc[r][1] = fmaf(dv.z, wqb.z, acc[r][1]);
                    acc[r][1] = fmaf(dv.w, wqb.w, acc[r][1]);
                }
            }

            // RMSProp + momentum update (identical to R1), x lives in LDS
#pragma unroll
            for (int r = 0; r < RTILE; ++r) {
#pragma unroll
                for (int c = 0; c < 2; ++c) {
                    const float xv  = x_lds[r][j0 + c];
                    const float g   = 2.f * acc[r][c] + 0.1f * xv * rsqrtf(xv * xv + 1e-6f);
                    const float na1 = 0.9f * a1[r][c] + 0.1f * g * g;
                    a1[r][c] = na1;
                    const float upd = 0.001f * g * rsqrtf(na1 + 1e-8f);
                    const float na2 = 0.9f * a2[r][c] - upd;
                    a2[r][c] = na2;
                    x_lds[r][j0 + c] = xv + 0.9f * na2 - upd;
                }
            }
            __syncthreads();
        }
    }

    // write final x (coalesced)
    for (int k = t; k < RTILE * DOUT; k += 256)
        out[row0 * DOUT + k] = (&x_lds[0][0])[k];
}

extern "C" void kernel_launch(void* const* d_in, const int* in_sizes, int n_in,
                              void* d_out, int out_size, void* d_ws, size_t ws_size,
                              hipStream_t stream) {
    const float* inputs = (const float*)d_in[0];
    const float* W      = (const float*)d_in[1];
    float* out          = (float*)d_out;
    float* W4           = (float*)d_ws;               // 256 KB
    float* Wt4          = (float*)d_ws + 65536;       // 256 KB

    sc_pack<<<dim3(256), dim3(256), 0, stream>>>(W, W4, Wt4);
    sc_fused<<<dim3(NBLOCKS), dim3(256), 0, stream>>>(inputs, (const float4*)W4,
                                                      (const float4*)Wt4, out);
}